// Round 1
// baseline (44.851 us; speedup 1.0000x reference)
//
#include <hip/hip_runtime.h>
#include <math.h>

#define NPTS 500000
#define MF 32
#define EMB 78        // 2*32 + 2*(2^3-1)
#define NQ 12
#define NC 25
#define BLK 256

__device__ __forceinline__ float fast_rcp(float x) { return __builtin_amdgcn_rcpf(x); }
__device__ __forceinline__ float satf(float x) { return fminf(fmaxf(x, 0.0f), 1.0f); }

__global__ __launch_bounds__(BLK) void pikan_fused(
    const float* __restrict__ xt,
    const float* __restrict__ Bf,
    const float* __restrict__ gamma,
    const float* __restrict__ beta,
    const float* __restrict__ W,
    const float* __restrict__ b_inner,
    const float* __restrict__ inner_scale,
    const float* __restrict__ coeffs,
    const float* __restrict__ a,
    const float* __restrict__ b_out,
    float* __restrict__ out,
    int npts)
{
    __shared__ float sc[NQ * NC];   // 1.2 KB spline coeffs
    for (int i = threadIdx.x; i < NQ * NC; i += BLK) sc[i] = coeffs[i];
    __syncthreads();

    const int n = blockIdx.x * BLK + threadIdx.x;
    if (n >= npts) return;

    const float2 p = reinterpret_cast<const float2*>(xt)[n];
    const float x = p.x, t = p.y;

    float emb[EMB];
    const float fscale = (float)(1.0 / (5.656854249492380195206754896838 + 1e-12)); // 1/(sqrt(32)+1e-12)

    // ---- Fourier features: sin(2*pi*dot), cos(2*pi*dot). HW sin takes revolutions.
    #pragma unroll
    for (int m = 0; m < MF; ++m) {
        float rev = x * Bf[2 * m] + t * Bf[2 * m + 1];
        float fr  = rev - floorf(rev);
        emb[m]      = __builtin_amdgcn_sinf(fr) * fscale;
        emb[MF + m] = __builtin_amdgcn_cosf(fr) * fscale;
    }

    // ---- Wavelet features (Mexican-hat), j = 0..2, per j: ux block then ut block
    {
        int o = 2 * MF;
        #pragma unroll
        for (int j = 0; j < 3; ++j) {
            const int nk = 1 << j;
            const float inv = (float)(2 * nk);   // 1/scale, scale = 0.5/nk (exact pow2)
            #pragma unroll
            for (int k = 0; k < nk; ++k) {
                float c = (k + 0.5f) / (float)nk;
                float v = (x - c) * inv;
                float v2 = v * v;
                emb[o + k] = (1.0f - v2) * __expf(-0.5f * v2);
            }
            #pragma unroll
            for (int k = 0; k < nk; ++k) {
                float c = (k + 0.5f) / (float)nk;
                float v = (t - c) * inv;
                float v2 = v * v;
                emb[o + nk + k] = (1.0f - v2) * __expf(-0.5f * v2);
            }
            o += 2 * nk;
        }
    }

    // ---- LayerNorm (two-pass, matches reference)
    float sum = 0.0f;
    #pragma unroll
    for (int e = 0; e < EMB; ++e) sum += emb[e];
    const float mu = sum * (1.0f / EMB);
    float vs = 0.0f;
    #pragma unroll
    for (int e = 0; e < EMB; ++e) { float d = emb[e] - mu; vs = fmaf(d, d, vs); }
    const float istd = rsqrtf(vs * (1.0f / EMB) + 1e-5f);
    #pragma unroll
    for (int e = 0; e < EMB; ++e)
        emb[e] = fmaf((emb[e] - mu) * istd, gamma[e], beta[e]);

    // ---- inner projection: u[q] = emb . W[q,:] + b_inner[q]  (W via scalar loads)
    float u[NQ];
    #pragma unroll
    for (int q = 0; q < NQ; ++q) {
        float acc = b_inner[q];
        #pragma unroll
        for (int e = 0; e < EMB; ++e) acc = fmaf(emb[e], W[q * EMB + e], acc);
        u[q] = acc;
    }

    // ---- tanh squash + span-local cubic de Boor + spline dot + output dot
    const float isc = inner_scale[0];
    const float c22 = (float)(1.0 / 22.0);
    float y = b_out[0];
    #pragma unroll
    for (int q = 0; q < NQ; ++q) {
        float s = 0.5f * (tanhf(isc * u[q]) + 1.0f);
        s = satf(s);
        int ii = (int)(s * 22.0f);           // span offset, i = ii + 3
        ii = ii > 21 ? 21 : ii;

        // knots: knot(idx) = sat((idx-3)/22); need idx = i-2 .. i+3
        float k_m2 = satf((float)(ii - 2) * c22);
        float k_m1 = satf((float)(ii - 1) * c22);
        float k_0  = satf((float)(ii)     * c22);
        float k_p1 = satf((float)(ii + 1) * c22);
        float k_p2 = satf((float)(ii + 2) * c22);
        float k_p3 = satf((float)(ii + 3) * c22);

        float l1 = s - k_0, l2 = s - k_m1, l3 = s - k_m2;
        float r1 = k_p1 - s, r2 = k_p2 - s, r3 = k_p3 - s;

        // de Boor triangle (all denominators > 0 in span-local form)
        float t0 = fast_rcp(r1 + l1);            // level 1
        float N0 = r1 * t0;
        float N1 = l1 * t0;

        float ta = N0 * fast_rcp(r1 + l2);       // level 2
        float tb = N1 * fast_rcp(r2 + l1);
        N0 = r1 * ta;
        N1 = fmaf(l2, ta, r2 * tb);
        float N2 = l1 * tb;

        float tc = N0 * fast_rcp(r1 + l3);       // level 3
        float td = N1 * fast_rcp(r2 + l2);
        float te = N2 * fast_rcp(r3 + l1);
        N0 = r1 * tc;
        N1 = fmaf(l3, tc, r2 * td);
        N2 = fmaf(l2, td, r3 * te);
        float N3 = l1 * te;

        const float* cq = sc + q * NC + ii;
        float phi = fmaf(N0, cq[0], fmaf(N1, cq[1], fmaf(N2, cq[2], N3 * cq[3])));
        y = fmaf(phi, a[q], y);
    }

    out[n] = y;
}

extern "C" void kernel_launch(void* const* d_in, const int* in_sizes, int n_in,
                              void* d_out, int out_size, void* d_ws, size_t ws_size,
                              hipStream_t stream) {
    const float* xt          = (const float*)d_in[0];
    const float* Bf          = (const float*)d_in[1];
    const float* gamma       = (const float*)d_in[2];
    const float* beta        = (const float*)d_in[3];
    const float* W           = (const float*)d_in[4];
    const float* b_inner     = (const float*)d_in[5];
    const float* inner_scale = (const float*)d_in[6];
    const float* coeffs      = (const float*)d_in[7];
    const float* a           = (const float*)d_in[8];
    const float* b_out       = (const float*)d_in[9];
    float* out = (float*)d_out;

    const int npts = in_sizes[0] / 2;
    const int grid = (npts + BLK - 1) / BLK;
    pikan_fused<<<grid, BLK, 0, stream>>>(xt, Bf, gamma, beta, W, b_inner,
                                          inner_scale, coeffs, a, b_out, out, npts);
}

// Round 2
// 32.323 us; speedup vs baseline: 1.3876x; 1.3876x over previous
//
#include <hip/hip_runtime.h>
#include <math.h>

#define MF 32
#define EMB 78        // 2*32 + 2*(2^3-1)
#define NQ 12
#define NC 25
#define NSPAN 22
#define BLK 256

// workspace layout (floats)
#define WS_WG 0                 // gamma*W, [e*NQ+q], 936
#define WS_SG (EMB*NQ)          // 12
#define WS_SB (WS_SG + NQ)      // 12
#define WS_P  (WS_SB + NQ)      // poly table [q][span][4], a-folded, 1056 (offset 960 floats = 3840 B, 16B aligned)

__device__ __forceinline__ float fast_rcp(float x) { return __builtin_amdgcn_rcpf(x); }
__device__ __forceinline__ float satf(float x) { return fminf(fmaxf(x, 0.0f), 1.0f); }

// cubic B-spline basis values N_{ii..ii+3} at s, span ii (0..21), open-uniform knots sat((idx-3)/22)
__device__ __forceinline__ float4 deboor4(float s, int ii) {
    const float c22 = 1.0f / 22.0f;
    float k_m2 = satf((float)(ii - 2) * c22);
    float k_m1 = satf((float)(ii - 1) * c22);
    float k_0  = satf((float)(ii)     * c22);
    float k_p1 = satf((float)(ii + 1) * c22);
    float k_p2 = satf((float)(ii + 2) * c22);
    float k_p3 = satf((float)(ii + 3) * c22);

    float l1 = s - k_0, l2 = s - k_m1, l3 = s - k_m2;
    float r1 = k_p1 - s, r2 = k_p2 - s, r3 = k_p3 - s;

    float t0 = fast_rcp(r1 + l1);
    float N0 = r1 * t0;
    float N1 = l1 * t0;

    float ta = N0 * fast_rcp(r1 + l2);
    float tb = N1 * fast_rcp(r2 + l1);
    N0 = r1 * ta;
    N1 = fmaf(l2, ta, r2 * tb);
    float N2 = l1 * tb;

    float tc = N0 * fast_rcp(r1 + l3);
    float td = N1 * fast_rcp(r2 + l2);
    float te = N2 * fast_rcp(r3 + l1);
    N0 = r1 * tc;
    N1 = fmaf(l3, tc, r2 * td);
    N2 = fmaf(l2, td, r3 * te);
    float N3 = l1 * te;
    return make_float4(N0, N1, N2, N3);
}

// one tiny block: fold gamma into W, precompute LN-fold scalars, and fit
// per-(q,span) cubic polys of a_q * phi_q(s) in local coord u = s*22 - span.
__global__ __launch_bounds__(256) void pikan_setup(
    const float* __restrict__ g, const float* __restrict__ be,
    const float* __restrict__ W, const float* __restrict__ bi,
    const float* __restrict__ coeffs, const float* __restrict__ a,
    float* __restrict__ ws)
{
    const int tid = threadIdx.x;
    for (int i = tid; i < EMB * NQ; i += 256) {
        int e = i / NQ, q = i - e * NQ;
        ws[WS_WG + i] = g[e] * W[q * EMB + e];
    }
    if (tid < NQ) {
        float sg = 0.f, sb = 0.f;
        for (int e = 0; e < EMB; ++e) {
            float w = W[tid * EMB + e];
            sg += g[e] * w;
            sb += be[e] * w;
        }
        ws[WS_SG + tid] = sg;
        ws[WS_SB + tid] = sb + bi[tid];
    }
    for (int i = tid; i < NQ * NSPAN; i += 256) {
        int q = i / NSPAN, ii = i - q * NSPAN;
        float f[4];
        #pragma unroll
        for (int j = 0; j < 4; ++j) {
            float u = (float)j / 3.0f;                       // 0, 1/3, 2/3, 1 (folded)
            float s = ((float)ii + u) * (1.0f / 22.0f);
            float4 N = deboor4(s, ii);
            const float* cq = coeffs + q * NC + ii;
            f[j] = N.x * cq[0] + N.y * cq[1] + N.z * cq[2] + N.w * cq[3];
        }
        // inverse Vandermonde for nodes {0,1/3,2/3,1}, monomial basis in u
        float c0 = f[0];
        float c1 = -5.5f * f[0] +  9.0f * f[1] -  4.5f * f[2] +  1.0f * f[3];
        float c2 =  9.0f * f[0] - 22.5f * f[1] + 18.0f * f[2] -  4.5f * f[3];
        float c3 = -4.5f * f[0] + 13.5f * f[1] - 13.5f * f[2] +  4.5f * f[3];
        float aq = a[q];
        reinterpret_cast<float4*>(ws + WS_P)[i] =
            make_float4(c0 * aq, c1 * aq, c2 * aq, c3 * aq);
    }
}

__global__ __launch_bounds__(BLK, 8) void pikan_main(
    const float* __restrict__ xt, const float* __restrict__ Bf,
    const float* __restrict__ isc_p, const float* __restrict__ bout_p,
    const float* __restrict__ ws, float* __restrict__ out, int npts)
{
    __shared__ float4 sP[NQ * NSPAN];   // 4224 B poly table
    for (int i = threadIdx.x; i < NQ * NSPAN; i += BLK)
        sP[i] = reinterpret_cast<const float4*>(ws + WS_P)[i];
    __syncthreads();

    const int n = blockIdx.x * BLK + threadIdx.x;
    if (n >= npts) return;

    const float2 p = reinterpret_cast<const float2*>(xt)[n];
    const float x = p.x, t = p.y;
    const float* __restrict__ Wg = ws + WS_WG;

    float A[NQ];
    #pragma unroll
    for (int q = 0; q < NQ; ++q) A[q] = 0.0f;
    float sum = 0.0f, ss = 0.0f;

    auto feed = [&](float f, int e) {
        sum += f;
        ss = fmaf(f, f, ss);
        #pragma unroll
        for (int q = 0; q < NQ; ++q) A[q] = fmaf(f, Wg[e * NQ + q], A[q]);
    };

    const float fscale = (float)(1.0 / (5.656854249492380195206754896838 + 1e-12));

    // Fourier: sin/cos of 2*pi*dot -> HW trans in revolutions, fract-reduced
    #pragma unroll
    for (int m = 0; m < MF; ++m) {
        float rev = fmaf(x, Bf[2 * m], t * Bf[2 * m + 1]);
#if __has_builtin(__builtin_amdgcn_fractf)
        float fr = __builtin_amdgcn_fractf(rev);
#else
        float fr = rev - floorf(rev);
#endif
        feed(__builtin_amdgcn_sinf(fr) * fscale, m);
        feed(__builtin_amdgcn_cosf(fr) * fscale, MF + m);
    }

    // Wavelets (Mexican hat), j=0..2, ux block then ut block
    {
        int e = 2 * MF;
        #pragma unroll
        for (int j = 0; j < 3; ++j) {
            const int nk = 1 << j;
            const float inv = (float)(2 * nk);
            #pragma unroll
            for (int k = 0; k < nk; ++k) {
                float c = ((float)k + 0.5f) / (float)nk;
                float v = (x - c) * inv, v2 = v * v;
                feed((1.0f - v2) * __expf(-0.5f * v2), e + k);
            }
            #pragma unroll
            for (int k = 0; k < nk; ++k) {
                float c = ((float)k + 0.5f) / (float)nk;
                float v = (t - c) * inv, v2 = v * v;
                feed((1.0f - v2) * __expf(-0.5f * v2), e + nk + k);
            }
            e += 2 * nk;
        }
    }

    // LN folded into the projection: u_q = istd*(A_q - mu*Sg_q) + Sb_q
    const float mu = sum * (1.0f / EMB);
    float var = fmaf(-mu, mu, ss * (1.0f / EMB));
    var = fmaxf(var, 0.0f);
    const float istd = rsqrtf(var + 1e-5f);
    const float kexp = -2.0f * isc_p[0] * 1.4426950408889634f;  // sigmoid: 1/(1+2^(k*u))

    float y = bout_p[0];
    #pragma unroll
    for (int q = 0; q < NQ; ++q) {
        float uq = fmaf(istd, A[q] - mu * (ws + WS_SG)[q], (ws + WS_SB)[q]);
        float s = fast_rcp(1.0f + __builtin_amdgcn_exp2f(kexp * uq));
        float v = s * 22.0f;
        int ii = (int)v;
        ii = ii > 21 ? 21 : ii;
        float u = v - (float)ii;
        float4 c = sP[q * NSPAN + ii];
        y += fmaf(fmaf(fmaf(c.w, u, c.z), u, c.y), u, c.x);
    }
    out[n] = y;
}

extern "C" void kernel_launch(void* const* d_in, const int* in_sizes, int n_in,
                              void* d_out, int out_size, void* d_ws, size_t ws_size,
                              hipStream_t stream) {
    const float* xt          = (const float*)d_in[0];
    const float* Bf          = (const float*)d_in[1];
    const float* gamma       = (const float*)d_in[2];
    const float* beta        = (const float*)d_in[3];
    const float* W           = (const float*)d_in[4];
    const float* b_inner     = (const float*)d_in[5];
    const float* inner_scale = (const float*)d_in[6];
    const float* coeffs      = (const float*)d_in[7];
    const float* a           = (const float*)d_in[8];
    const float* b_out       = (const float*)d_in[9];
    float* out = (float*)d_out;
    float* ws  = (float*)d_ws;

    const int npts = in_sizes[0] / 2;
    pikan_setup<<<1, 256, 0, stream>>>(gamma, beta, W, b_inner, coeffs, a, ws);
    const int grid = (npts + BLK - 1) / BLK;
    pikan_main<<<grid, BLK, 0, stream>>>(xt, Bf, inner_scale, b_out, ws, out, npts);
}

// Round 3
// 25.149 us; speedup vs baseline: 1.7834x; 1.2852x over previous
//
#include <hip/hip_runtime.h>
#include <hip/hip_bf16.h>
#include <math.h>

#define MF 32
#define EMB 78        // 2*32 + 2*(2^3-1)
#define NQ 12
#define NC 25
#define NSPAN 22
#define BLK 256
#define FSCALE 0.17677669529663688f   // 1/(sqrt(32)+1e-12)

typedef __attribute__((ext_vector_type(8))) short short8;
typedef __attribute__((ext_vector_type(4))) float f32x4;

// ws layout (dwords)
#define WS_A    0      // A fragments: 3 ktiles * 64 lanes * 4 dwords (bf16x2)
#define WS_SGSB 768    // (Sg,Sb) pairs, 16 q
#define WS_P    800    // poly table 16*22 float4 (byte 3200, 16B aligned)

__device__ __forceinline__ float fast_rcp(float x) { return __builtin_amdgcn_rcpf(x); }
__device__ __forceinline__ float satf(float x) { return fminf(fmaxf(x, 0.0f), 1.0f); }

__device__ __forceinline__ unsigned pack2(float a, float b) {
    __hip_bfloat16 ha = __float2bfloat16(a), hb = __float2bfloat16(b);
    unsigned short ua, ub;
    __builtin_memcpy(&ua, &ha, 2); __builtin_memcpy(&ub, &hb, 2);
    return (unsigned)ua | ((unsigned)ub << 16);
}

// cubic B-spline basis N_{ii..ii+3} at s, span ii, open-uniform knots sat((idx-3)/22)
__device__ __forceinline__ float4 deboor4(float s, int ii) {
    const float c22 = 1.0f / 22.0f;
    float k_m2 = satf((float)(ii - 2) * c22);
    float k_m1 = satf((float)(ii - 1) * c22);
    float k_0  = satf((float)(ii)     * c22);
    float k_p1 = satf((float)(ii + 1) * c22);
    float k_p2 = satf((float)(ii + 2) * c22);
    float k_p3 = satf((float)(ii + 3) * c22);
    float l1 = s - k_0, l2 = s - k_m1, l3 = s - k_m2;
    float r1 = k_p1 - s, r2 = k_p2 - s, r3 = k_p3 - s;
    float t0 = fast_rcp(r1 + l1);
    float N0 = r1 * t0, N1 = l1 * t0;
    float ta = N0 * fast_rcp(r1 + l2);
    float tb = N1 * fast_rcp(r2 + l1);
    N0 = r1 * ta;
    N1 = fmaf(l2, ta, r2 * tb);
    float N2 = l1 * tb;
    float tc = N0 * fast_rcp(r1 + l3);
    float td = N1 * fast_rcp(r2 + l2);
    float te = N2 * fast_rcp(r3 + l1);
    N0 = r1 * tc;
    N1 = fmaf(l3, tc, r2 * td);
    N2 = fmaf(l2, td, r3 * te);
    float N3 = l1 * te;
    return make_float4(N0, N1, N2, N3);
}

__device__ __forceinline__ float wgf(const float* g, const float* W, int q, int k) {
    if (q >= NQ || k >= EMB) return 0.0f;
    float v = g[k] * W[q * EMB + k];
    return (k < 2 * MF) ? v * FSCALE : v;
}

__global__ __launch_bounds__(256) void pikan_setup(
    const float* __restrict__ g, const float* __restrict__ be,
    const float* __restrict__ W, const float* __restrict__ bi,
    const float* __restrict__ coeffs, const float* __restrict__ a,
    float* __restrict__ ws)
{
    const int tid = threadIdx.x;
    unsigned* wsu = (unsigned*)ws;

    // A fragments: lane l holds A[q=l&15][k = kt*32 + (l>>4)*8 + 2d .. +1]
    for (int i = tid; i < 768; i += 256) {
        int d = i & 3, l = (i >> 2) & 63, kt = i >> 8;
        int q = l & 15;
        int kb = kt * 32 + (l >> 4) * 8 + d * 2;
        wsu[WS_A + i] = pack2(wgf(g, W, q, kb), wgf(g, W, q, kb + 1));
    }
    // Sg/Sb (full f32 precision)
    if (tid < 16) {
        float sg = 0.f, sb = 0.f;
        if (tid < NQ) {
            for (int e = 0; e < EMB; ++e) {
                float w = W[tid * EMB + e];
                sg += g[e] * w;
                sb += be[e] * w;
            }
            sb += bi[tid];
        }
        ws[WS_SGSB + 2 * tid]     = sg;
        ws[WS_SGSB + 2 * tid + 1] = sb;
    }
    // per-(q,span) cubic poly of a_q*phi_q in local u = s*22 - span; q>=12 zeroed
    for (int i = tid; i < 16 * NSPAN; i += 256) {
        int q = i / NSPAN, ii = i - q * NSPAN;
        float4 o = make_float4(0.f, 0.f, 0.f, 0.f);
        if (q < NQ) {
            float f[4];
            #pragma unroll
            for (int j = 0; j < 4; ++j) {
                float u = (float)j / 3.0f;
                float s = ((float)ii + u) * (1.0f / 22.0f);
                float4 N = deboor4(s, ii);
                const float* cq = coeffs + q * NC + ii;
                f[j] = N.x * cq[0] + N.y * cq[1] + N.z * cq[2] + N.w * cq[3];
            }
            float c0 = f[0];
            float c1 = -5.5f * f[0] +  9.0f * f[1] -  4.5f * f[2] +  1.0f * f[3];
            float c2 =  9.0f * f[0] - 22.5f * f[1] + 18.0f * f[2] -  4.5f * f[3];
            float c3 = -4.5f * f[0] + 13.5f * f[1] - 13.5f * f[2] +  4.5f * f[3];
            float aq = a[q];
            o = make_float4(c0 * aq, c1 * aq, c2 * aq, c3 * aq);
        }
        reinterpret_cast<float4*>(ws + WS_P)[i] = o;
    }
}

__global__ __launch_bounds__(BLK, 4) void pikan_main(
    const float* __restrict__ xt, const float* __restrict__ Bf,
    const float* __restrict__ isc_p, const float* __restrict__ bout_p,
    const float* __restrict__ ws, float* __restrict__ out, int npts)
{
    __shared__ uint4  sEmb[4][256];          // per-wave 4KB staging (64 rows x 4 slots)
    __shared__ float4 sPoly[16 * NSPAN];

    const int tid = threadIdx.x;
    for (int i = tid; i < 16 * NSPAN; i += BLK)
        sPoly[i] = reinterpret_cast<const float4*>(ws + WS_P)[i];
    __syncthreads();

    const int l = tid & 63, w = tid >> 6;
    const int g16 = l >> 4, c16 = l & 15;
    const int sw = (l >> 1) & 3;             // slot swizzle; (p>>1)&3 == (c16>>1)&3 on reads
    uint4* myEmb = sEmb[w];

    float sgq[4], sbq[4];
    #pragma unroll
    for (int r = 0; r < 4; ++r) {
        int q = g16 * 4 + r;
        sgq[r] = ws[WS_SGSB + 2 * q];
        sbq[r] = ws[WS_SGSB + 2 * q + 1];
    }
    const float kexp = -2.0f * isc_p[0] * 1.4426950408889634f;
    const float bout = bout_p[0];
    const int base = (blockIdx.x * 4 + w) * 128;

    #pragma unroll 1
    for (int pass = 0; pass < 2; ++pass) {
        const int pbase = base + pass * 64;
        const int pt = pbase + l;
        const bool valid = pt < npts;
        float x = 0.f, t = 0.f;
        if (valid) { float2 p = reinterpret_cast<const float2*>(xt)[pt]; x = p.x; t = p.y; }

        f32x4 acc[4];
        #pragma unroll
        for (int n = 0; n < 4; ++n) acc[n] = (f32x4){0.f, 0.f, 0.f, 0.f};

        auto stage = [&](uint4 a0, uint4 a1, uint4 a2, uint4 a3) {
            myEmb[l * 4 + (0 ^ sw)] = a0;
            myEmb[l * 4 + (1 ^ sw)] = a1;
            myEmb[l * 4 + (2 ^ sw)] = a2;
            myEmb[l * 4 + (3 ^ sw)] = a3;
        };
        auto mfma_kt = [&](int kt) {
            uint4 au = reinterpret_cast<const uint4*>(ws)[kt * 64 + l];
            short8 af = __builtin_bit_cast(short8, au);
            #pragma unroll
            for (int n = 0; n < 4; ++n) {
                int p = n * 16 + c16;
                uint4 bu = myEmb[p * 4 + (g16 ^ sw)];
                short8 bf = __builtin_bit_cast(short8, bu);
                acc[n] = __builtin_amdgcn_mfma_f32_16x16x32_bf16(af, bf, acc[n], 0, 0, 0);
            }
        };

        // ---- Fourier: raw sin/cos staged (fscale folded into A); f32 stats kept exact
        float sumf = 0.f, ssf = 0.f;
        unsigned spk[16], cpk[16];
        #pragma unroll
        for (int mp = 0; mp < 16; ++mp) {
            float rev0 = fmaf(x, Bf[4 * mp + 0], t * Bf[4 * mp + 1]);
            float rev1 = fmaf(x, Bf[4 * mp + 2], t * Bf[4 * mp + 3]);
#if __has_builtin(__builtin_amdgcn_fractf)
            float f0 = __builtin_amdgcn_fractf(rev0);
            float f1 = __builtin_amdgcn_fractf(rev1);
#else
            float f0 = rev0 - floorf(rev0);
            float f1 = rev1 - floorf(rev1);
#endif
            float s0 = __builtin_amdgcn_sinf(f0), s1 = __builtin_amdgcn_sinf(f1);
            float c0 = __builtin_amdgcn_cosf(f0), c1 = __builtin_amdgcn_cosf(f1);
            sumf += (s0 + s1) + (c0 + c1);
            ssf = fmaf(s0, s0, fmaf(s1, s1, fmaf(c0, c0, fmaf(c1, c1, ssf))));
            spk[mp] = pack2(s0, s1);
            cpk[mp] = pack2(c0, c1);
        }
        stage(make_uint4(spk[0], spk[1], spk[2],  spk[3]),
              make_uint4(spk[4], spk[5], spk[6],  spk[7]),
              make_uint4(spk[8], spk[9], spk[10], spk[11]),
              make_uint4(spk[12], spk[13], spk[14], spk[15]));
        mfma_kt(0);
        stage(make_uint4(cpk[0], cpk[1], cpk[2],  cpk[3]),
              make_uint4(cpk[4], cpk[5], cpk[6],  cpk[7]),
              make_uint4(cpk[8], cpk[9], cpk[10], cpk[11]),
              make_uint4(cpk[12], cpk[13], cpk[14], cpk[15]));
        mfma_kt(1);

        // ---- Wavelets (Mexican hat), e=64..77, zero-padded to 96
        float w14[14];
        float sumw = 0.f, ssw = 0.f;
        {
            int o = 0;
            #pragma unroll
            for (int j = 0; j < 3; ++j) {
                const int nk = 1 << j;
                const float inv = (float)(2 * nk);
                #pragma unroll
                for (int k = 0; k < nk; ++k) {
                    float c = ((float)k + 0.5f) / (float)nk;
                    float v = (x - c) * inv, v2 = v * v;
                    float f = (1.0f - v2) * __expf(-0.5f * v2);
                    w14[o + k] = f; sumw += f; ssw = fmaf(f, f, ssw);
                }
                #pragma unroll
                for (int k = 0; k < nk; ++k) {
                    float c = ((float)k + 0.5f) / (float)nk;
                    float v = (t - c) * inv, v2 = v * v;
                    float f = (1.0f - v2) * __expf(-0.5f * v2);
                    w14[o + nk + k] = f; sumw += f; ssw = fmaf(f, f, ssw);
                }
                o += 2 * nk;
            }
        }
        stage(make_uint4(pack2(w14[0], w14[1]), pack2(w14[2], w14[3]),
                         pack2(w14[4], w14[5]), pack2(w14[6], w14[7])),
              make_uint4(pack2(w14[8], w14[9]), pack2(w14[10], w14[11]),
                         pack2(w14[12], w14[13]), 0u),
              make_uint4(0u, 0u, 0u, 0u),
              make_uint4(0u, 0u, 0u, 0u));
        mfma_kt(2);

        // ---- LN scalars (exact f32 path)
        const float sum = fmaf(FSCALE, sumf, sumw);
        const float ssq = fmaf(FSCALE * FSCALE, ssf, ssw);
        const float mu = sum * (1.0f / EMB);
        float var = fmaf(-mu, mu, ssq * (1.0f / EMB));
        var = fmaxf(var, 0.0f);
        const float istd = rsqrtf(var + 1e-5f);

        // ---- epilogue: sigmoid + spline poly per (q,point); reduce q across lanes
        float yout = 0.f;
        #pragma unroll
        for (int n = 0; n < 4; ++n) {
            float mun  = __shfl(mu,   n * 16 + c16);
            float istn = __shfl(istd, n * 16 + c16);
            float yn = 0.f;
            #pragma unroll
            for (int r = 0; r < 4; ++r) {
                float uq = fmaf(istn, fmaf(-mun, sgq[r], acc[n][r]), sbq[r]);
                float e2 = __builtin_amdgcn_exp2f(kexp * uq);
                float s = fast_rcp(1.0f + e2);
                float v = s * 22.0f;
                int ii = (int)v; ii = ii > 21 ? 21 : ii;
                float uu = v - (float)ii;
                float4 cc = sPoly[(g16 * 4 + r) * NSPAN + ii];
                yn += fmaf(fmaf(fmaf(cc.w, uu, cc.z), uu, cc.y), uu, cc.x);
            }
            yn += __shfl_xor(yn, 16);
            yn += __shfl_xor(yn, 32);
            if (g16 == n) yout = yn;
        }
        if (valid) out[pt] = yout + bout;
    }
}

extern "C" void kernel_launch(void* const* d_in, const int* in_sizes, int n_in,
                              void* d_out, int out_size, void* d_ws, size_t ws_size,
                              hipStream_t stream) {
    const float* xt          = (const float*)d_in[0];
    const float* Bf          = (const float*)d_in[1];
    const float* gamma       = (const float*)d_in[2];
    const float* beta        = (const float*)d_in[3];
    const float* W           = (const float*)d_in[4];
    const float* b_inner     = (const float*)d_in[5];
    const float* inner_scale = (const float*)d_in[6];
    const float* coeffs      = (const float*)d_in[7];
    const float* a           = (const float*)d_in[8];
    const float* b_out       = (const float*)d_in[9];
    float* out = (float*)d_out;
    float* ws  = (float*)d_ws;

    const int npts = in_sizes[0] / 2;
    pikan_setup<<<1, 256, 0, stream>>>(gamma, beta, W, b_inner, coeffs, a, ws);
    const int grid = (npts + 511) / 512;     // 512 points per block (2 per thread)
    pikan_main<<<grid, BLK, 0, stream>>>(xt, Bf, inner_scale, b_out, ws, out, npts);
}